// Round 9
// baseline (28.037 us; speedup 1.0000x reference)
//
#include <hip/hip_runtime.h>
#include <math.h>

// Problem constants (B=8, N=M=4096, D=2)
#define NPTS  4096
#define BQ    64      // queries per block
#define RQ    8       // queries per thread
#define SLOTS 8       // BQ/RQ threads span the query tile
#define NS    64      // chunk groups (512 threads / SLOTS)
#define NPAIR 32      // float4 point-pairs per chunk (NPTS/NS/2)
#define PSTR  33      // padded float4 stride per chunk (conflict-free banks)

typedef float f32x2 __attribute__((ext_vector_type(2)));

// Packed dual-FP32 FMA: d.lo = a.lo*b.lo + c.lo ; d.hi = a.hi*b.hi + c.hi
static __device__ __forceinline__ f32x2 pk_fma2(f32x2 a, f32x2 b, f32x2 c) {
    f32x2 d;
    asm("v_pk_fma_f32 %0, %1, %2, %3" : "=v"(d) : "v"(a), "v"(b), "v"(c));
    return d;
}
static __device__ __forceinline__ float min3f(float a, float b, float c) {
    float d;
    asm("v_min3_f32 %0, %1, %2, %3" : "=v"(d) : "v"(a), "v"(b), "v"(c));
    return d;
}

// grid 1024 = 2 dirs x 8 batches x 64 query-tiles; 512 thr; 3 blocks/CU.
__global__ __launch_bounds__(512, 6) void chamfer_main(
    const float* __restrict__ x, const float* __restrict__ tgt,
    float* __restrict__ partials)
{
    __shared__ float4 sm[NS * PSTR];   // 2112 float4 = 33.8 KB (padded)
    __shared__ float  red[8 * BQ];     // 2 KB cross-wave partial mins

    const int bx  = blockIdx.x;
    const int dir = bx >> 9;           // 0: queries=x stream=target, 1: swapped
    const int b   = (bx >> 6) & 7;
    const int qt  = bx & 63;           // 64 query tiles of 64
    const int t   = threadIdx.x;
    const int lane = t & 63, w = t >> 6;

    const float* qarr = dir ? tgt : x;
    const float* sarr = dir ? x   : tgt;

    // ---- stage stream points, padded: pair index i -> i + i/32 ----
    const float4* sp4 = (const float4*)(sarr + b * (NPTS * 2));
    #pragma unroll
    for (int k = 0; k < 4; ++k) {
        const int i = t + k * 512;
        sm[i + (i >> 5)] = sp4[i];
    }

    // ---- per-thread query setup: RQ=8 queries, coeffs duplicated in pairs ----
    const int slot = t & (SLOTS - 1);
    const int s    = t >> 3;           // chunk id 0..63
    const float2* qp = (const float2*)(qarr + b * (NPTS * 2));
    f32x2 qx2[RQ], qy2[RQ];
    float m[RQ];
    #pragma unroll
    for (int r = 0; r < RQ; ++r) {
        const float2 p = qp[qt * BQ + slot + SLOTS * r];
        const float nx = -2.f * p.x, ny = -2.f * p.y;
        qx2[r].x = nx; qx2[r].y = nx;
        qy2[r].x = ny; qy2[r].y = ny;
        m[r] = INFINITY;
    }
    __syncthreads();

    // ---- inner loop: 1 ds_read_b128 (2 pts) -> ~30 VALU via v_pk_fma_f32 ----
    const float4* tp = sm + s * PSTR;
    #pragma unroll 2
    for (int j = 0; j < NPAIR; ++j) {
        const float4 t4 = tp[j];
        f32x2 XX; XX.x = t4.x; XX.y = t4.z;
        f32x2 YY; YY.x = t4.y; YY.y = t4.w;
        f32x2 Z;
        Z.x = fmaf(t4.x, t4.x, t4.y * t4.y);
        Z.y = fmaf(t4.z, t4.z, t4.w * t4.w);
        #pragma unroll
        for (int r = 0; r < RQ; ++r) {
            f32x2 d = pk_fma2(YY, qy2[r], Z);   // y*ny + |p|^2   (both points)
            d = pk_fma2(XX, qx2[r], d);         // + x*nx
            m[r] = min3f(m[r], d.x, d.y);
        }
    }

    // fold query norm: |q|^2 = 0.25*(nx^2+ny^2); min(m)+pp == min(m+pp)
    #pragma unroll
    for (int r = 0; r < RQ; ++r)
        m[r] += 0.25f * fmaf(qx2[r].x, qx2[r].x, qy2[r].x * qy2[r].x);

    // ---- intra-wave reduce across the 8 chunk-subgroups (lane bits 3..5) ----
    #pragma unroll
    for (int r = 0; r < RQ; ++r) {
        m[r] = fminf(m[r], __shfl_xor(m[r], 8));
        m[r] = fminf(m[r], __shfl_xor(m[r], 16));
        m[r] = fminf(m[r], __shfl_xor(m[r], 32));
    }
    if (lane < SLOTS) {
        #pragma unroll
        for (int r = 0; r < RQ; ++r) red[w * BQ + lane + SLOTS * r] = m[r];
    }
    __syncthreads();

    // ---- cross-wave min (8 waves) + sqrt + block sum (wave 0) ----
    if (t < BQ) {
        float mm = red[t];
        #pragma unroll
        for (int ww = 1; ww < 8; ++ww) mm = fminf(mm, red[ww * BQ + t]);
        float v = sqrtf(fmaxf(mm, 0.f));
        v += __shfl_down(v, 32);
        v += __shfl_down(v, 16);
        v += __shfl_down(v, 8);
        v += __shfl_down(v, 4);
        v += __shfl_down(v, 2);
        v += __shfl_down(v, 1);
        if (t == 0) partials[bx] = v;
    }
}

__global__ __launch_bounds__(256) void chamfer_final(
    const float* __restrict__ partials, float* __restrict__ out)
{
    __shared__ float red[256];
    const int tid = threadIdx.x;
    red[tid] = partials[tid] + partials[tid + 256] +
               partials[tid + 512] + partials[tid + 768];
    __syncthreads();
    if (tid < 64) {
        float s = red[tid] + red[tid + 64] + red[tid + 128] + red[tid + 192];
        s += __shfl_down(s, 32);
        s += __shfl_down(s, 16);
        s += __shfl_down(s, 8);
        s += __shfl_down(s, 4);
        s += __shfl_down(s, 2);
        s += __shfl_down(s, 1);
        // mean(d_t_to_x) + mean(d_x_to_t): both halves divide by B*4096 = 32768
        if (tid == 0) out[0] = s * (1.0f / 32768.0f);
    }
}

extern "C" void kernel_launch(void* const* d_in, const int* in_sizes, int n_in,
                              void* d_out, int out_size, void* d_ws, size_t ws_size,
                              hipStream_t stream) {
    const float* x   = (const float*)d_in[0];
    const float* tgt = (const float*)d_in[1];
    float* partials  = (float*)d_ws;   // 1024 floats
    float* out       = (float*)d_out;  // 1 float

    chamfer_main<<<dim3(1024), dim3(512), 0, stream>>>(x, tgt, partials);
    chamfer_final<<<dim3(1),   dim3(256), 0, stream>>>(partials, out);
}